// Round 1
// baseline (107.449 us; speedup 1.0000x reference)
//
#include <hip/hip_runtime.h>

// KV Q4 dequantizer.
// Layout facts (from reference):
//  - packed: [BATCH * N_BLOCKS * 16] int32, each int holds 2 nibbles (low, high)
//  - scale/bias: [BATCH * N_BLOCKS] fp32, one per 32-value block (= 16 packed ints)
//  - output: flat fp32 stream, K then V; out[2p] = low(p)*s+b, out[2p+1] = high(p)*s+b
// Memory-bound: ~36 MiB in, ~64 MiB out. One thread per int4 (4 ints -> 8 floats).

__global__ __launch_bounds__(256) void kv_dequant_kernel(
    const int4* __restrict__ k_packed, const float* __restrict__ k_scale,
    const float* __restrict__ k_bias,
    const int4* __restrict__ v_packed, const float* __restrict__ v_scale,
    const float* __restrict__ v_bias,
    float4* __restrict__ out_k, float4* __restrict__ out_v, int n4)
{
    int tid = blockIdx.x * blockDim.x + threadIdx.x;
    if (tid >= n4) return;

    const int4*  src;
    const float* sc;
    const float* bi;
    float4*      dst;
    if (blockIdx.y == 0) { src = k_packed; sc = k_scale; bi = k_bias; dst = out_k; }
    else                 { src = v_packed; sc = v_scale; bi = v_bias; dst = out_v; }

    int4 p = src[tid];

    // 4 packed ints per thread, 16 packed ints per quant block -> block idx = tid/4
    int blk = tid >> 2;
    float s = sc[blk];
    float b = bi[blk];

    float4 f0, f1;
    f0.x = fmaf((float)( p.x        & 15), s, b);
    f0.y = fmaf((float)((p.x >> 4)  & 15), s, b);
    f0.z = fmaf((float)( p.y        & 15), s, b);
    f0.w = fmaf((float)((p.y >> 4)  & 15), s, b);
    f1.x = fmaf((float)( p.z        & 15), s, b);
    f1.y = fmaf((float)((p.z >> 4)  & 15), s, b);
    f1.z = fmaf((float)( p.w        & 15), s, b);
    f1.w = fmaf((float)((p.w >> 4)  & 15), s, b);

    dst[tid * 2]     = f0;
    dst[tid * 2 + 1] = f1;
}

extern "C" void kernel_launch(void* const* d_in, const int* in_sizes, int n_in,
                              void* d_out, int out_size, void* d_ws, size_t ws_size,
                              hipStream_t stream) {
    const int4*  k_packed = (const int4*)d_in[0];
    const float* k_scale  = (const float*)d_in[1];
    const float* k_bias   = (const float*)d_in[2];
    const int4*  v_packed = (const int4*)d_in[3];
    const float* v_scale  = (const float*)d_in[4];
    const float* v_bias   = (const float*)d_in[5];

    int n_packed = in_sizes[0];        // total int32s in k_packed (= v_packed)
    int n4       = n_packed / 4;       // int4 units per tensor
    long long k_out_elems = (long long)n_packed * 2;  // 2 floats per packed int

    float4* out_k = (float4*)d_out;
    float4* out_v = (float4*)((float*)d_out + k_out_elems);

    dim3 block(256);
    dim3 grid((n4 + 255) / 256, 2);
    kv_dequant_kernel<<<grid, block, 0, stream>>>(
        k_packed, k_scale, k_bias, v_packed, v_scale, v_bias, out_k, out_v, n4);
}

// Round 2
// 106.352 us; speedup vs baseline: 1.0103x; 1.0103x over previous
//
#include <hip/hip_runtime.h>

// KV Q4 dequantizer, v2.
// Layout facts (from reference):
//  - packed: [BATCH * N_BLOCKS * 16] int32, each int holds 2 nibbles (low, high)
//  - scale/bias: [BATCH * N_BLOCKS] fp32, one per 32-value block (= 16 packed ints)
//  - output: flat fp32 stream, K then V; out[2p] = low(p)*s+b, out[2p+1] = high(p)*s+b
// v2: one int2 per thread -> exactly one float4 store per thread, perfectly
// coalesced (lane i stores at base+16i). v1's dst[2*tid]/dst[2*tid+1] pattern
// was 32 B-strided per store instruction (50% per-instruction coalescing).

__global__ __launch_bounds__(256) void kv_dequant_kernel(
    const int2* __restrict__ k_packed, const float* __restrict__ k_scale,
    const float* __restrict__ k_bias,
    const int2* __restrict__ v_packed, const float* __restrict__ v_scale,
    const float* __restrict__ v_bias,
    float4* __restrict__ out_k, float4* __restrict__ out_v, int n2)
{
    int tid = blockIdx.x * blockDim.x + threadIdx.x;
    if (tid >= n2) return;

    const int2*  src;
    const float* sc;
    const float* bi;
    float4*      dst;
    if (blockIdx.y == 0) { src = k_packed; sc = k_scale; bi = k_bias; dst = out_k; }
    else                 { src = v_packed; sc = v_scale; bi = v_bias; dst = out_v; }

    int2 p = src[tid];

    // 2 packed ints per thread, 16 packed ints per quant block -> block idx = tid/8
    int blk = tid >> 3;
    float s = sc[blk];
    float b = bi[blk];

    float4 f;
    f.x = fmaf((float)( p.x       & 15), s, b);
    f.y = fmaf((float)((p.x >> 4) & 15), s, b);
    f.z = fmaf((float)( p.y       & 15), s, b);
    f.w = fmaf((float)((p.y >> 4) & 15), s, b);

    dst[tid] = f;
}

extern "C" void kernel_launch(void* const* d_in, const int* in_sizes, int n_in,
                              void* d_out, int out_size, void* d_ws, size_t ws_size,
                              hipStream_t stream) {
    const int2*  k_packed = (const int2*)d_in[0];
    const float* k_scale  = (const float*)d_in[1];
    const float* k_bias   = (const float*)d_in[2];
    const int2*  v_packed = (const int2*)d_in[3];
    const float* v_scale  = (const float*)d_in[4];
    const float* v_bias   = (const float*)d_in[5];

    int n_packed = in_sizes[0];        // total int32s in k_packed (= v_packed)
    int n2       = n_packed / 2;       // int2 units per tensor
    long long k_out_elems = (long long)n_packed * 2;  // 2 floats per packed int

    float4* out_k = (float4*)d_out;
    float4* out_v = (float4*)((float*)d_out + k_out_elems);

    dim3 block(256);
    dim3 grid((n2 + 255) / 256, 2);
    kv_dequant_kernel<<<grid, block, 0, stream>>>(
        k_packed, k_scale, k_bias, v_packed, v_scale, v_bias, out_k, out_v, n2);
}